// Round 5
// baseline (39659.180 us; speedup 1.0000x reference)
//
#include <hip/hip_runtime.h>
#include <hip/hip_bf16.h>
#include <math.h>

#define T_STEPS 2048
#define N_MOD   64
#define N_HID   256
#define N_INP   128

typedef unsigned long long ull;

// Relaxed agent-scope (sc1) atomics — coherent across XCDs via LLC.
#define AG_LD64(p)   __hip_atomic_load((p),      __ATOMIC_RELAXED, __HIP_MEMORY_SCOPE_AGENT)
#define AG_ST64(p,v) __hip_atomic_store((p),(v), __ATOMIC_RELAXED, __HIP_MEMORY_SCOPE_AGENT)

// --------------------------------------------------------------------------
// Pre-pass: xpre[t,n,h] = sum_i x2h[n,h,i] * x[t,i]  -> fb_seq region of d_out.
// Stepping kernel reads xpre[t] (prefetched) then overwrites with fb[t].
// --------------------------------------------------------------------------
__global__ __launch_bounds__(256, 2) void xpre_kernel(
    const float* __restrict__ x, const float* __restrict__ x2h,
    float* __restrict__ out)
{
  __shared__ float xl[64 * N_INP];
  const int tb = blockIdx.x;
  const int n  = blockIdx.y;
  const int t  = threadIdx.x;

  const float4* xs  = (const float4*)(x + (size_t)tb * 64 * N_INP);
  float4*       xld = (float4*)xl;
  for (int k = t; k < 64 * N_INP / 4; k += 256) xld[k] = xs[k];

  float w[N_INP];
  const float* wrow = x2h + ((size_t)n * N_HID + t) * N_INP;
#pragma unroll
  for (int j = 0; j < N_INP; j += 4) {
    const float4 a = *(const float4*)(wrow + j);
    w[j] = a.x; w[j+1] = a.y; w[j+2] = a.z; w[j+3] = a.w;
  }
  __syncthreads();

  for (int tt = 0; tt < 64; ++tt) {
    float a0=0.f, a1=0.f, a2=0.f, a3=0.f;
#pragma unroll
    for (int j = 0; j < N_INP; j += 4) {
      const float4 h4 = *(const float4*)&xl[tt * N_INP + j];
      a0 = fmaf(w[j],   h4.x, a0);
      a1 = fmaf(w[j+1], h4.y, a1);
      a2 = fmaf(w[j+2], h4.z, a2);
      a3 = fmaf(w[j+3], h4.w, a3);
    }
    out[((size_t)(tb*64 + tt) * N_MOD + n) * N_HID + t] = (a0+a1)+(a2+a3);
  }
}

// --------------------------------------------------------------------------
// Persistent stepping kernel: 64 WGs x 512 threads, one WG per module.
// Thread t: h = t&255, c = t>>8. wv[128] = wm[h, c*128:+128) fp32, loaded
// through a VOLATILE pointer -> compiler cannot rematerialize -> stays in
// VGPRs (R2/R3 failure mode: plain const loads were re-streamed every step).
//
// v-formulation: fb[m] = sum_mm conn[m,mm] * v[mm],  v[m] = wm @ hy[m].
// Exchange carries (fp32 v, u32 step-tag) in one 8B relaxed agent atomic —
// the tag IS the flag (equality spin; no fences, no flags).
//
// Iter k:
//   BAR_R: redr_k, xring ready
//   g(t<256): update rows: pre = xpre_k + r_k + bias + fb_k -> tanh ->
//             Euler -> hy_{k+1} -> LDS; oring[k&3] = {hy,hz,fb_k}
//   BAR_A: hy_{k+1} visible
//   ALL:  redv[t] = wv . hy[c-half]   (VGPR x LDS, 128 FMA)
//   BAR_V
//   g: v[h] = redv[h]+redv[h+256]; publish (v, k+1) -> hbt[(k+1)&1];
//      gather 64 tagged v's (4 batches of 16, depth-2 pipelined);
//      fb_{k+1} = conn-weighted sum (register)
//   s: (k%4==3): flush 4 steps {states,fb} from oring; refill xring;
//      then redr_{k+1}[hs] = h2h[m,hs,:] . hy_{k+1}  (256KB L2 stream,
//      fills the gather window)
//
// Reuse safety: publish of tag k+2 into parity k&1 happens only after that
// WG finished gathering tags k+1; seeing ALL tags k+1 implies every WG
// finished gathering tags k (same parity) — so no un-read slot is ever
// overwritten. Equality-spin makes leftover tags from previous replays
// read as stale (plus hbt is memset to 0 each launch).
// --------------------------------------------------------------------------
__global__ __launch_bounds__(512, 2)
void archnet_step(
    const float* __restrict__ init, const float* __restrict__ wm,
    const float* __restrict__ conn, const float* __restrict__ h2h,
    const float* __restrict__ bias,
    float* __restrict__ out_states, float* __restrict__ out_fb,
    ull* hbt)
{
  __shared__ float hyv_lds[N_HID];        // 1 KB
  __shared__ float redr[N_HID];           // 1 KB
  __shared__ float redv[512];             // 2 KB
  __shared__ float conn4[N_MOD];          // 256 B
  __shared__ float xring[4 * N_HID];      // 4 KB
  __shared__ float oring[4 * 3 * N_HID];  // 12 KB

  const int m = blockIdx.x;               // module
  const int t = threadIdx.x;              // 0..511
  const int h = t & 255;
  const int c = t >> 8;                   // 0 or 1

  // ---- wm half-row resident in VGPRs (volatile: cannot rematerialize) ----
  float wv[128];
  {
    const volatile float* wp = wm + (size_t)h * N_HID + c * 128;
#pragma unroll
    for (int j = 0; j < 128; ++j) wv[j] = wp[j];
  }

  // ---- init ----
  float hyv = 0.f, hzv = 0.f, biasv = 0.f, fbv = 0.f;
  if (t < N_HID) {
    hyv   = init[(size_t)m * 512 + h];
    hzv   = init[(size_t)m * 512 + 256 + h];
    biasv = bias[(size_t)m * N_HID + h];
    hyv_lds[h] = hyv;
    out_states[(size_t)m * 512 + h]       = hyv;   // states_seq[0]
    out_states[(size_t)m * 512 + 256 + h] = hzv;
  } else {
    const int hs = t - 256;
#pragma unroll
    for (int i = 0; i < 4; ++i)          // xring preload: steps 0..3
      xring[i * N_HID + hs] = out_fb[((size_t)i * N_MOD + m) * N_HID + hs];
  }
  if (t < N_MOD) conn4[t] = conn[m * N_MOD + t];
  __syncthreads();

  // ---- pre-loop: redr_0 (s-half) ----
  if (t >= 256) {
    const int hs = t - 256;
    const float* hr = h2h + ((size_t)m * N_HID + hs) * N_HID;
    float r0=0.f, r1=0.f, r2=0.f, r3=0.f;
#pragma unroll 8
    for (int j = 0; j < N_HID; j += 4) {
      const float4 a = *(const float4*)(hr + j);
      const float4 q = *(const float4*)(&hyv_lds[j]);
      r0 = fmaf(a.x, q.x, r0); r1 = fmaf(a.y, q.y, r1);
      r2 = fmaf(a.z, q.z, r2); r3 = fmaf(a.w, q.w, r3);
    }
    redr[hs] = (r0+r1)+(r2+r3);
  }

  for (int k = 0; k < T_STEPS; ++k) {
    __syncthreads();                      // BAR_R

    if (t < N_HID) {
      // ---- A: update ----
      const float xq  = xring[(k & 3) * N_HID + h];
      const float pre = xq + redr[h] + biasv + fbv;
      const float th  = tanhf(pre);
      hzv = hzv + 0.01f * (th - hyv - hzv);   // GAMMA=EPS=1, DT=0.01
      hyv = hyv + 0.01f * hzv;
      hyv_lds[h] = hyv;
      oring[(k & 3) * 768 + h]       = hyv;
      oring[(k & 3) * 768 + 256 + h] = hzv;
      oring[(k & 3) * 768 + 512 + h] = fbv;   // fb_seq[k]
    }

    __syncthreads();                      // BAR_A: hy_{k+1} visible

    // ---- v-partial: all 512 threads, VGPR wm x LDS hy ----
    {
      const float4* hy4 = (const float4*)(&hyv_lds[c * 128]);
      float a0=0.f, a1=0.f, a2=0.f, a3=0.f;
#pragma unroll
      for (int j = 0; j < 32; ++j) {
        const float4 q = hy4[j];
        a0 = fmaf(wv[4*j],   q.x, a0);
        a1 = fmaf(wv[4*j+1], q.y, a1);
        a2 = fmaf(wv[4*j+2], q.z, a2);
        a3 = fmaf(wv[4*j+3], q.w, a3);
      }
      redv[t] = (a0+a1)+(a2+a3);
    }

    __syncthreads();                      // BAR_V

    if (k + 1 < T_STEPS) {
      if (t < N_HID) {
        // ---- publish (v, tag k+1) ----
        const unsigned want = (unsigned)(k + 1);
        ull* hb = hbt + (size_t)((k + 1) & 1) * (N_MOD * N_HID);
        const float vv = redv[h] + redv[h + 256];
        AG_ST64(&hb[(size_t)m * N_HID + h],
                ((ull)want << 32) | (ull)__float_as_uint(vv));

        // ---- gather: 4 batches of 16 modules, depth-2 pipelined ----
        float acc = 0.f;
        ull B0[16], B1[16];
#define GISSUE(BUF, BASE) \
        _Pragma("unroll") for (int i = 0; i < 16; ++i) \
          BUF[i] = AG_LD64(&hb[(size_t)((BASE) + i) * N_HID + h]);
#define GRESOLVE(BUF, BASE) { \
        bool again = true; \
        while (again) { again = false; \
          _Pragma("unroll") for (int i = 0; i < 16; ++i) { \
            if ((unsigned)(BUF[i] >> 32) != want) { \
              BUF[i] = AG_LD64(&hb[(size_t)((BASE) + i) * N_HID + h]); again = true; } } } \
        _Pragma("unroll") for (int i = 0; i < 16; i += 4) { \
          const float4 cf = *(const float4*)&conn4[(BASE) + i]; \
          acc = fmaf(cf.x, __uint_as_float((unsigned)BUF[i+0]), acc); \
          acc = fmaf(cf.y, __uint_as_float((unsigned)BUF[i+1]), acc); \
          acc = fmaf(cf.z, __uint_as_float((unsigned)BUF[i+2]), acc); \
          acc = fmaf(cf.w, __uint_as_float((unsigned)BUF[i+3]), acc); } }
        GISSUE(B0, 0); GISSUE(B1, 16);
        GRESOLVE(B0, 0);  GISSUE(B0, 32);
        GRESOLVE(B1, 16); GISSUE(B1, 48);
        GRESOLVE(B0, 32);
        GRESOLVE(B1, 48);
#undef GISSUE
#undef GRESOLVE
        fbv = acc;                        // fb_{k+1}
      } else {
        const int hs = t - 256;
        // ---- batched output flush + xpre refill (every 4 steps) ----
        if ((k & 3) == 3) {
#pragma unroll
          for (int i = 0; i < 4; ++i) {
            const int st = k - 3 + i;
            const float hv = oring[i * 768 + hs];
            const float zv = oring[i * 768 + 256 + hs];
            const float fv = oring[i * 768 + 512 + hs];
            const size_t ob = ((size_t)(st + 1) * N_MOD + m) * 512;
            out_states[ob + hs]       = hv;
            out_states[ob + 256 + hs] = zv;
            out_fb[((size_t)st * N_MOD + m) * N_HID + hs] = fv;
          }
#pragma unroll
          for (int i = 0; i < 4; ++i) {
            const int st2 = k + 1 + i;
            if (st2 < T_STEPS)
              xring[(st2 & 3) * N_HID + hs] =
                  out_fb[((size_t)st2 * N_MOD + m) * N_HID + hs];
          }
        }
        // ---- h2h stream: redr_{k+1}[hs] (fills gather window) ----
        const float* hr = h2h + ((size_t)m * N_HID + hs) * N_HID;
        float r0=0.f, r1=0.f, r2=0.f, r3=0.f;
#pragma unroll 8
        for (int j = 0; j < N_HID; j += 4) {
          const float4 a = *(const float4*)(hr + j);
          const float4 q = *(const float4*)(&hyv_lds[j]);
          r0 = fmaf(a.x, q.x, r0); r1 = fmaf(a.y, q.y, r1);
          r2 = fmaf(a.z, q.z, r2); r3 = fmaf(a.w, q.w, r3);
        }
        redr[hs] = (r0+r1)+(r2+r3);
      }
    } else {
      // final iter: flush last 4 steps (k == 2047, k&3 == 3)
      if (t >= 256) {
        const int hs = t - 256;
#pragma unroll
        for (int i = 0; i < 4; ++i) {
          const int st = k - 3 + i;
          const float hv = oring[i * 768 + hs];
          const float zv = oring[i * 768 + 256 + hs];
          const float fv = oring[i * 768 + 512 + hs];
          const size_t ob = ((size_t)(st + 1) * N_MOD + m) * 512;
          out_states[ob + hs]       = hv;
          out_states[ob + 256 + hs] = zv;
          out_fb[((size_t)st * N_MOD + m) * N_HID + hs] = fv;
        }
      }
    }
  }
}

// --------------------------------------------------------------------------
extern "C" void kernel_launch(void* const* d_in, const int* in_sizes, int n_in,
                              void* d_out, int out_size, void* d_ws, size_t ws_size,
                              hipStream_t stream) {
  const float* x    = (const float*)d_in[0];   // (2048,128)
  const float* init = (const float*)d_in[1];   // (64,2,256)
  const float* wmw  = (const float*)d_in[2];   // (256,256)
  const float* conn = (const float*)d_in[3];   // (64,64)
  const float* x2h  = (const float*)d_in[4];   // (64,256,128)
  const float* h2h  = (const float*)d_in[5];   // (64,256,256)
  const float* bias = (const float*)d_in[6];   // (64,256)

  float* out_states = (float*)d_out;                                        // (2049,64,2,256)
  float* out_fb     = out_states + (size_t)(T_STEPS+1) * N_MOD * 2 * N_HID; // (2048,64,256)

  // workspace: tagged v exchange, double-buffered: 2 * 64*256 * 8B = 256 KB
  ull* hbt = (ull*)d_ws;
  hipMemsetAsync(d_ws, 0, (size_t)2 * N_MOD * N_HID * 8, stream);

  xpre_kernel<<<dim3(T_STEPS/64, N_MOD), dim3(256), 0, stream>>>(x, x2h, out_fb);

  void* args[] = {
    (void*)&init, (void*)&wmw, (void*)&conn, (void*)&h2h, (void*)&bias,
    (void*)&out_states, (void*)&out_fb, (void*)&hbt
  };
  hipLaunchCooperativeKernel((void*)archnet_step, dim3(64), dim3(512),
                             args, 0, stream);
}

// Round 6
// 16421.500 us; speedup vs baseline: 2.4151x; 2.4151x over previous
//
#include <hip/hip_runtime.h>
#include <hip/hip_bf16.h>
#include <math.h>

#define T_STEPS 2048
#define N_MOD   64
#define N_HID   256
#define N_INP   128

// --------------------------------------------------------------------------
// init: states_seq[0] = initial_states
// --------------------------------------------------------------------------
__global__ __launch_bounds__(512) void init_kernel(
    const float* __restrict__ init, float* __restrict__ out_states)
{
  const int idx = blockIdx.x * 512 + threadIdx.x;   // 64*512 = 32768 elems
  out_states[idx] = init[idx];
}

// --------------------------------------------------------------------------
// Pre-pass: xpre[t,n,h] = sum_i x2h[n,h,i] * x[t,i]  -> fb_seq region of d_out.
// Step kernel k reads xpre[k] then overwrites it with fb[k] (same thread,
// read-before-write -> deterministic across graph replays).
// --------------------------------------------------------------------------
__global__ __launch_bounds__(256, 2) void xpre_kernel(
    const float* __restrict__ x, const float* __restrict__ x2h,
    float* __restrict__ out)
{
  __shared__ float xl[64 * N_INP];
  const int tb = blockIdx.x;
  const int n  = blockIdx.y;
  const int t  = threadIdx.x;

  const float4* xs  = (const float4*)(x + (size_t)tb * 64 * N_INP);
  float4*       xld = (float4*)xl;
  for (int k = t; k < 64 * N_INP / 4; k += 256) xld[k] = xs[k];

  float w[N_INP];
  const float* wrow = x2h + ((size_t)n * N_HID + t) * N_INP;
#pragma unroll
  for (int j = 0; j < N_INP; j += 4) {
    const float4 a = *(const float4*)(wrow + j);
    w[j] = a.x; w[j+1] = a.y; w[j+2] = a.z; w[j+3] = a.w;
  }
  __syncthreads();

  for (int tt = 0; tt < 64; ++tt) {
    float a0=0.f, a1=0.f, a2=0.f, a3=0.f;
#pragma unroll
    for (int j = 0; j < N_INP; j += 4) {
      const float4 h4 = *(const float4*)&xl[tt * N_INP + j];
      a0 = fmaf(w[j],   h4.x, a0);
      a1 = fmaf(w[j+1], h4.y, a1);
      a2 = fmaf(w[j+2], h4.z, a2);
      a3 = fmaf(w[j+3], h4.w, a3);
    }
    out[((size_t)(tb*64 + tt) * N_MOD + n) * N_HID + t] = (a0+a1)+(a2+a3);
  }
}

// --------------------------------------------------------------------------
// One kernel per timestep. Kernel boundary = global barrier (no atomics).
// Grid: 256 WGs x 256 threads; WG (m = b>>2, q = b&3) owns rows
// h in [q*64, q*64+64) of module m.
//
// u-formulation: fb[m] = wm @ u[m],  u[m,j] = sum_mm conn[m,mm]*hy_k[mm,j].
// The two 256-dot matvecs (h2h row . hy_k[m]) and (wm row . u) are
// independent -> full ILP overlap within one phase.
//
// Thread i: ro = i&63 (row offset), jq = i>>6 (64-wide j-chunk).
// Phase 1: hym -> LDS; u[i] via 64 coalesced broadcast loads of hy_k;
//          threads i<64 prefetch update inputs (xpre, hy, hz, bias).
// Phase 2: dual quarter-row matvecs -> redr/redf (LDS).
// Phase 3: threads i<64: reduce 4 chunks, tanh Euler update, store
//          states_seq[k+1] and fb_seq[k] (fb=0 exactly at k=0).
// --------------------------------------------------------------------------
__global__ __launch_bounds__(256) void step_kernel(
    int k, const float* __restrict__ wm, const float* __restrict__ conn,
    const float* __restrict__ h2h, const float* __restrict__ bias,
    float* __restrict__ out_states, float* __restrict__ out_fb)
{
  const int b  = blockIdx.x;
  const int m  = b >> 2;
  const int q  = b & 3;
  const int i  = threadIdx.x;       // 0..255
  const int ro = i & 63;
  const int jq = i >> 6;

  __shared__ float hym[N_HID];
  __shared__ float u[N_HID];
  __shared__ float redr[256];
  __shared__ float redf[256];

  const float* hyk = out_states + (size_t)k * N_MOD * 512;

  // ---- phase 1: own-module hy -> LDS; u[i]; prefetch update inputs ----
  hym[i] = hyk[(size_t)m * 512 + i];
  {
    float ua=0.f, ub=0.f, uc=0.f, ud=0.f;
#pragma unroll
    for (int mm = 0; mm < N_MOD; mm += 4) {
      ua = fmaf(conn[m * N_MOD + mm + 0], hyk[(size_t)(mm + 0) * 512 + i], ua);
      ub = fmaf(conn[m * N_MOD + mm + 1], hyk[(size_t)(mm + 1) * 512 + i], ub);
      uc = fmaf(conn[m * N_MOD + mm + 2], hyk[(size_t)(mm + 2) * 512 + i], uc);
      ud = fmaf(conn[m * N_MOD + mm + 3], hyk[(size_t)(mm + 3) * 512 + i], ud);
    }
    u[i] = (ua + ub) + (uc + ud);
  }
  float xq = 0.f, hyv = 0.f, hzv = 0.f, bv = 0.f;
  if (i < 64) {
    const int hu = q * 64 + i;
    xq  = out_fb[((size_t)k * N_MOD + m) * N_HID + hu];   // xpre[k]
    hyv = hyk[(size_t)m * 512 + hu];
    hzv = hyk[(size_t)m * 512 + 256 + hu];
    bv  = bias[m * N_HID + hu];
  }
  __syncthreads();

  // ---- phase 2: dual quarter-row matvecs ----
  {
    const int h = q * 64 + ro;
    const float* hrow = h2h + ((size_t)m * N_HID + h) * N_HID + jq * 64;
    const float* wrow = wm  + (size_t)h * N_HID + jq * 64;
    float r0=0.f, r1=0.f, r2=0.f, r3=0.f;
    float f0=0.f, f1=0.f, f2=0.f, f3=0.f;
#pragma unroll
    for (int j = 0; j < 64; j += 4) {
      const float4 a  = *(const float4*)(hrow + j);
      const float4 w4 = *(const float4*)(wrow + j);
      const float4 hv = *(const float4*)(&hym[jq * 64 + j]);
      const float4 uv = *(const float4*)(&u[jq * 64 + j]);
      r0 = fmaf(a.x, hv.x, r0);  f0 = fmaf(w4.x, uv.x, f0);
      r1 = fmaf(a.y, hv.y, r1);  f1 = fmaf(w4.y, uv.y, f1);
      r2 = fmaf(a.z, hv.z, r2);  f2 = fmaf(w4.z, uv.z, f2);
      r3 = fmaf(a.w, hv.w, r3);  f3 = fmaf(w4.w, uv.w, f3);
    }
    redr[i] = (r0 + r1) + (r2 + r3);
    redf[i] = (f0 + f1) + (f2 + f3);
  }
  __syncthreads();

  // ---- phase 3: reduce + update + store (one thread per owned row) ----
  if (i < 64) {
    const int hu = q * 64 + i;
    const float r  = (redr[i] + redr[i + 64]) + (redr[i + 128] + redr[i + 192]);
    const float fb = (k == 0) ? 0.f
                   : (redf[i] + redf[i + 64]) + (redf[i + 128] + redf[i + 192]);
    const float pre = xq + r + bv + fb;
    const float th  = tanhf(pre);
    const float hzn = hzv + 0.01f * (th - hyv - hzv);   // GAMMA=EPS=1, DT=0.01
    const float hyn = hyv + 0.01f * hzn;
    const size_t ob = ((size_t)(k + 1) * N_MOD + m) * 512;
    out_states[ob + hu]       = hyn;
    out_states[ob + 256 + hu] = hzn;
    out_fb[((size_t)k * N_MOD + m) * N_HID + hu] = fb;  // overwrite xpre[k]
  }
}

// --------------------------------------------------------------------------
extern "C" void kernel_launch(void* const* d_in, const int* in_sizes, int n_in,
                              void* d_out, int out_size, void* d_ws, size_t ws_size,
                              hipStream_t stream) {
  const float* x    = (const float*)d_in[0];   // (2048,128)
  const float* init = (const float*)d_in[1];   // (64,2,256)
  const float* wmw  = (const float*)d_in[2];   // (256,256)
  const float* conn = (const float*)d_in[3];   // (64,64)
  const float* x2h  = (const float*)d_in[4];   // (64,256,128)
  const float* h2h  = (const float*)d_in[5];   // (64,256,256)
  const float* bias = (const float*)d_in[6];   // (64,256)

  float* out_states = (float*)d_out;                                        // (2049,64,2,256)
  float* out_fb     = out_states + (size_t)(T_STEPS+1) * N_MOD * 2 * N_HID; // (2048,64,256)

  init_kernel<<<64, 512, 0, stream>>>(init, out_states);
  xpre_kernel<<<dim3(T_STEPS/64, N_MOD), dim3(256), 0, stream>>>(x, x2h, out_fb);

  for (int k = 0; k < T_STEPS; ++k) {
    step_kernel<<<256, 256, 0, stream>>>(k, wmw, conn, h2h, bias,
                                         out_states, out_fb);
  }
}